// Round 5
// baseline (319.567 us; speedup 1.0000x reference)
//
#include <hip/hip_runtime.h>
#include <hip/hip_bf16.h>
#include <math.h>
#include <stdint.h>

// Problem constants (fixed by the reference)
#define S_LEN  8192
#define DMODEL 512
#define NBATCH 4

// gemm_m tiling
constexpr int BM = 128, BN = 128, BK = 32;
constexpr int PK = 40;                    // padded LDS row stride (shorts); 80 B = 16B-aligned

// gemm_c tiling
constexpr int CBK = 32;
constexpr int PKC = 40;

// Workspace layout (bytes):
//   Mred  @ 0          : 4 MB   (4 x 512 x 512 f32)
//   vws   @ 4MB        : 8 KB   (4 x 512 f32)
//   Mpart @ 4MB+8KB    : NS*16*NBATCH tiles x 64 KB  (NS=16: 64 MB, NS=8: 32 MB)
//   vpart @ after Mpart: NS*NBATCH*4 rows x 2 KB
constexpr size_t MRED_OFF  = 0;
constexpr size_t VWS_OFF   = (size_t)NBATCH * DMODEL * DMODEL * 4;          // 4 MB
constexpr size_t MPART_OFF = VWS_OFF + (size_t)NBATCH * DMODEL * 4;         // +8 KB

__host__ __device__ constexpr size_t mpart_elems(int ns) {
  return (size_t)NBATCH * ns * 16 * (BM * BN);
}
__host__ __device__ constexpr size_t vpart_elems(int ns) {
  return (size_t)ns * NBATCH * 4 * DMODEL;
}
__host__ __device__ constexpr size_t ws_need(int ns) {
  return MPART_OFF + (mpart_elems(ns) + vpart_elems(ns)) * 4;
}

typedef short bfrag  __attribute__((ext_vector_type(8)));   // 8 bf16 (4 VGPRs)
typedef float facc   __attribute__((ext_vector_type(4)));   // 4 fp32 acc

__device__ __forceinline__ unsigned pk2(float a, float b) {
  // packed RNE fp32->bf16 pair; lowers to v_cvt_pk_bf16_f32 on gfx950
  __hip_bfloat162 t = __float22bfloat162_rn(make_float2(a, b));
  union { __hip_bfloat162 h; unsigned u; } cc; cc.h = t; return cc.u;
}

__device__ __forceinline__ void atomAddF(float* p, float v) {
  unsafeAtomicAdd(p, v);
}

__device__ __forceinline__ float selc(const float4& v, int c) {
  return c == 0 ? v.x : c == 1 ? v.y : c == 2 ? v.z : v.w;
}

// ---------------------------------------------------------------------------
// Kernel 1: partial M[b][d'][d] = sum_{t in chunk} w_t h[b][t][d'] e[b][t][d]
// Register-prefetch pipeline; packed bf16 conversion; plain-store epilogue
// (ATOMIC=false) or atomicAdd fallback (ATOMIC=true).
// ---------------------------------------------------------------------------
template <int NS, bool ATOMIC>
__global__ __launch_bounds__(256, 4) void gemm_m_kernel(
    const float* __restrict__ h, const float* __restrict__ e,
    float* __restrict__ Mout, float* __restrict__ vout)
{
  __shared__ short Al[BM * PK];
  __shared__ short Bl[BN * PK];

  constexpr int KCH = S_LEN / NS;

  const int blk = blockIdx.x;          // grid = NBATCH * NS * 16
  const int nt  = blk & 3;
  const int mt  = (blk >> 2) & 3;
  const int kt  = (blk >> 4) & (NS - 1);
  const int bb  = blk / (16 * NS);

  const int tid   = threadIdx.x;
  const bool isB  = (tid >= 128);      // wave-uniform (waves 2,3)
  const int hid   = tid & 127;
  const int col4  = (hid & 31) * 4;    // 4-col group within the 128-wide tile
  const int trow  = hid >> 5;          // 0..3 -> t-rows trow*8 .. trow*8+7

  const int wv   = tid >> 6;           // wave 0..3 -> 2x2 of 64x64 subtiles
  const int wm   = wv >> 1, wn = wv & 1;
  const int lane = tid & 63;
  const int lm   = lane & 15, q = lane >> 4;

  const float* src = (isB ? e : h) + (size_t)bb * S_LEN * DMODEL
                   + (isB ? nt * BN : mt * BM) + col4;
  short* ldst = (isB ? Bl : Al) + col4 * PK + trow * 8;

  facc acc[4][4];
#pragma unroll
  for (int i = 0; i < 4; ++i)
#pragma unroll
    for (int j = 0; j < 4; ++j) acc[i][j] = (facc){0.f, 0.f, 0.f, 0.f};

  const float lnA = -(float)M_PI / (float)S_LEN;   // log(alpha), negative
  const int tstart = kt * KCH, tend = tstart + KCH;

  float wbase = __expf(lnA * (float)(S_LEN - 1 - tstart - trow * 8));
  const float stepw = __expf(-lnA * (float)BK);    // alpha^(-32)
  float cr[8];
#pragma unroll
  for (int r = 0; r < 8; ++r)
    cr[r] = __expf(-lnA * (float)r);               // alpha^(-r)

  float4 vacc4 = {0.f, 0.f, 0.f, 0.f};

  // ---- preload iter 0 ----
  float4 cur[8];
  {
    const float* p = src + (size_t)(tstart + trow * 8) * DMODEL;
#pragma unroll
    for (int r = 0; r < 8; ++r) cur[r] = *(const float4*)(p + (size_t)r * DMODEL);
  }

  for (int t0 = tstart; t0 < tend; t0 += BK) {
    // ---- scale (B only) + v accumulate ----
    if (isB) {
#pragma unroll
      for (int r = 0; r < 8; ++r) {
        const float w = wbase * cr[r];
        cur[r].x *= w; cur[r].y *= w; cur[r].z *= w; cur[r].w *= w;
      }
      if (mt == 0) {
#pragma unroll
        for (int r = 0; r < 8; ++r) {
          vacc4.x += cur[r].x; vacc4.y += cur[r].y;
          vacc4.z += cur[r].z; vacc4.w += cur[r].w;
        }
      }
    }
    wbase *= stepw;

    // ---- packed bf16 convert + register transpose (frees cur) ----
    uint4 pk[4];
#pragma unroll
    for (int c = 0; c < 4; ++c) {
      pk[c].x = pk2(selc(cur[0], c), selc(cur[1], c));
      pk[c].y = pk2(selc(cur[2], c), selc(cur[3], c));
      pk[c].z = pk2(selc(cur[4], c), selc(cur[5], c));
      pk[c].w = pk2(selc(cur[6], c), selc(cur[7], c));
    }

    // ---- issue next tile's loads (prefetch distance ~= one iteration) ----
    if (t0 + BK < tend) {
      const float* p = src + (size_t)(t0 + BK + trow * 8) * DMODEL;
#pragma unroll
      for (int r = 0; r < 8; ++r) cur[r] = *(const float4*)(p + (size_t)r * DMODEL);
    }

    __syncthreads();   // previous iteration's frag reads done
#pragma unroll
    for (int c = 0; c < 4; ++c)
      *(uint4*)(ldst + c * PK) = pk[c];
    __syncthreads();

    bfrag af[4], bf[4];
#pragma unroll
    for (int i = 0; i < 4; ++i)
      af[i] = *(const bfrag*)&Al[(wm * 64 + i * 16 + lm) * PK + q * 8];
#pragma unroll
    for (int j = 0; j < 4; ++j)
      bf[j] = *(const bfrag*)&Bl[(wn * 64 + j * 16 + lm) * PK + q * 8];
#pragma unroll
    for (int i = 0; i < 4; ++i)
#pragma unroll
      for (int j = 0; j < 4; ++j)
        acc[i][j] = __builtin_amdgcn_mfma_f32_16x16x32_bf16(af[i], bf[j], acc[i][j], 0, 0, 0);
  }

  if (ATOMIC) {
    float* Mb = Mout + (size_t)bb * DMODEL * DMODEL;
#pragma unroll
    for (int i = 0; i < 4; ++i)
#pragma unroll
      for (int j = 0; j < 4; ++j)
#pragma unroll
        for (int r = 0; r < 4; ++r) {
          const int row = mt * BM + wm * 64 + i * 16 + q * 4 + r;
          const int col = nt * BN + wn * 64 + j * 16 + lm;
          atomAddF(&Mb[(size_t)row * DMODEL + col], acc[i][j][r]);
        }
    if (isB && mt == 0) {
      float* vp = &vout[bb * DMODEL + nt * BN + col4];
      atomAddF(vp + 0, vacc4.x); atomAddF(vp + 1, vacc4.y);
      atomAddF(vp + 2, vacc4.z); atomAddF(vp + 3, vacc4.w);
    }
  } else {
    float* Mp = Mout + (size_t)blk * (BM * BN);
#pragma unroll
    for (int i = 0; i < 4; ++i)
#pragma unroll
      for (int j = 0; j < 4; ++j)
#pragma unroll
        for (int r = 0; r < 4; ++r) {
          const int row = wm * 64 + i * 16 + q * 4 + r;   // local d'
          const int col = wn * 64 + j * 16 + lm;          // local d
          Mp[row * BN + col] = acc[i][j][r];
        }
    if (isB && mt == 0) {
      *(float4*)&vout[(size_t)((kt * NBATCH + bb) * 4 + trow) * DMODEL
                      + nt * BN + col4] = vacc4;
    }
  }
}

// ---------------------------------------------------------------------------
// Reduce: Mred = sum_kt Mpart; vws = sum_{kt,trow} vpart.  262144 threads.
// ---------------------------------------------------------------------------
template <int NS>
__global__ __launch_bounds__(256) void reduce_kernel(
    const float* __restrict__ Mpart, const float* __restrict__ vpart,
    float* __restrict__ Mred, float* __restrict__ vws)
{
  const int gid = blockIdx.x * 256 + threadIdx.x;    // 0 .. 262143 (one float4 each)
  const int bb     = gid >> 16;          // 65536 float4 per batch
  const int rem    = gid & 65535;
  const int tile   = rem >> 12;          // 16 tiles (mt*4+nt)
  const int within = rem & 4095;         // float4 index inside 128x128 tile

  const size_t tilesz = BM * BN;
  const size_t base = ((size_t)(bb * NS) * 16 + tile) * tilesz + (size_t)within * 4;
  float4 s = {0.f, 0.f, 0.f, 0.f};
#pragma unroll
  for (int kt = 0; kt < NS; ++kt) {
    const float4 v = *(const float4*)&Mpart[base + (size_t)kt * 16 * tilesz];
    s.x += v.x; s.y += v.y; s.z += v.z; s.w += v.w;
  }
  const int r = within >> 5;             // local row 0..127
  const int c = (within & 31) * 4;       // local col (float4-aligned)
  const int mt = tile >> 2, nt = tile & 3;
  *(float4*)&Mred[(size_t)bb * DMODEL * DMODEL
                  + (size_t)(mt * BM + r) * DMODEL + nt * BN + c] = s;

  if (gid < (NBATCH * DMODEL / 4)) {     // 512 threads: v reduction
    const int vb = gid >> 7;
    const int vc = (gid & 127) * 4;
    float4 vs = {0.f, 0.f, 0.f, 0.f};
#pragma unroll
    for (int kt = 0; kt < NS; ++kt)
#pragma unroll
      for (int tr = 0; tr < 4; ++tr) {
        const float4 v = *(const float4*)&vpart[(size_t)((kt * NBATCH + vb) * 4 + tr) * DMODEL + vc];
        vs.x += v.x; vs.y += v.y; vs.z += v.z; vs.w += v.w;
      }
    *(float4*)&vws[vb * DMODEL + vc] = vs;
  }
}

// ---------------------------------------------------------------------------
// Kernel 3: C[b][s][d] = sum_{d'} W[s][d'] Mred[b][d'][d] + bias[s]*v[b][d]
// 64x64 tiles, K=512, 16 pipelined iters, plain stores.
// ---------------------------------------------------------------------------
__global__ __launch_bounds__(256) void gemm_c_kernel(
    const float* __restrict__ Wmat, const float* __restrict__ bias,
    const float* __restrict__ Mred, const float* __restrict__ vws,
    float* __restrict__ out)
{
  __shared__ short Wl[64 * PKC];
  __shared__ short Ml[64 * PKC];

  const int blk = blockIdx.x;          // grid = 4 * 8 * 8 = 256
  const int ntc = blk & 7;
  const int mtc = (blk >> 3) & 7;
  const int bb  = blk >> 6;

  const int tid  = threadIdx.x;
  const bool isM = (tid >= 128);
  const int hid  = tid & 127;
  const int arow = hid & 63;           // W-half
  const int ahalf = (hid >> 6) * 16;
  const int mcol4 = (hid & 15) * 4;    // M-half
  const int mrow4 = (hid >> 4) * 4;

  const int wv   = tid >> 6;
  const int lane = tid & 63;
  const int lm   = lane & 15, q = lane >> 4;

  const float* Mb = Mred + (size_t)bb * DMODEL * DMODEL;

  facc acc[4];
#pragma unroll
  for (int j = 0; j < 4; ++j) acc[j] = (facc){0.f, 0.f, 0.f, 0.f};

  float4 cur[4];
  if (!isM) {
    const float* p = &Wmat[(size_t)(mtc * 64 + arow) * DMODEL + ahalf];
#pragma unroll
    for (int r = 0; r < 4; ++r) cur[r] = *(const float4*)(p + r * 4);
  } else {
    const float* p = Mb + (size_t)mrow4 * DMODEL + ntc * 64 + mcol4;
#pragma unroll
    for (int r = 0; r < 4; ++r) cur[r] = *(const float4*)(p + (size_t)r * DMODEL);
  }

  for (int k0 = 0; k0 < DMODEL; k0 += CBK) {
    uint4 pw0;
    uint2 pm[4];
    if (!isM) {
      pw0.x = pk2(cur[0].x, cur[0].y); pw0.y = pk2(cur[0].z, cur[0].w);
      pw0.z = pk2(cur[1].x, cur[1].y); pw0.w = pk2(cur[1].z, cur[1].w);
      // second 8 handled below via a second uint4 built from cur[2],cur[3]
    }
    uint4 pw1;
    if (!isM) {
      pw1.x = pk2(cur[2].x, cur[2].y); pw1.y = pk2(cur[2].z, cur[2].w);
      pw1.z = pk2(cur[3].x, cur[3].y); pw1.w = pk2(cur[3].z, cur[3].w);
    } else {
#pragma unroll
      for (int c = 0; c < 4; ++c) {
        pm[c].x = pk2(selc(cur[0], c), selc(cur[1], c));
        pm[c].y = pk2(selc(cur[2], c), selc(cur[3], c));
      }
    }

    if (k0 + CBK < DMODEL) {
      if (!isM) {
        const float* p = &Wmat[(size_t)(mtc * 64 + arow) * DMODEL + k0 + CBK + ahalf];
#pragma unroll
        for (int r = 0; r < 4; ++r) cur[r] = *(const float4*)(p + r * 4);
      } else {
        const float* p = Mb + (size_t)(k0 + CBK + mrow4) * DMODEL + ntc * 64 + mcol4;
#pragma unroll
        for (int r = 0; r < 4; ++r) cur[r] = *(const float4*)(p + (size_t)r * DMODEL);
      }
    }

    __syncthreads();
    if (!isM) {
      *(uint4*)&Wl[arow * PKC + ahalf]     = pw0;   // 8 shorts (k 0..7 of this half)
      *(uint4*)&Wl[arow * PKC + ahalf + 8] = pw1;
    } else {
#pragma unroll
      for (int c = 0; c < 4; ++c)
        *(uint2*)&Ml[(mcol4 + c) * PKC + mrow4] = pm[c];
    }
    __syncthreads();

    bfrag af, bf[4];
    af = *(const bfrag*)&Wl[(wv * 16 + lm) * PKC + q * 8];
#pragma unroll
    for (int j = 0; j < 4; ++j)
      bf[j] = *(const bfrag*)&Ml[(j * 16 + lm) * PKC + q * 8];
#pragma unroll
    for (int j = 0; j < 4; ++j)
      acc[j] = __builtin_amdgcn_mfma_f32_16x16x32_bf16(af, bf[j], acc[j], 0, 0, 0);
  }

#pragma unroll
  for (int j = 0; j < 4; ++j)
#pragma unroll
    for (int r = 0; r < 4; ++r) {
      const int row = mtc * 64 + wv * 16 + q * 4 + r;   // s
      const int col = ntc * 64 + j * 16 + lm;           // d
      out[((size_t)bb * DMODEL + row) * DMODEL + col] =
          acc[j][r] + bias[row] * vws[bb * DMODEL + col];
    }
}

// ---------------------------------------------------------------------------
extern "C" void kernel_launch(void* const* d_in, const int* in_sizes, int n_in,
                              void* d_out, int out_size, void* d_ws, size_t ws_size,
                              hipStream_t stream) {
  const float* h    = (const float*)d_in[0];   // (4, 8192, 512) fp32
  const float* e    = (const float*)d_in[1];   // (4, 8192, 512) fp32
  const float* Wmat = (const float*)d_in[2];   // (512, 512) fp32
  const float* bias = (const float*)d_in[3];   // (512,) fp32
  float* out = (float*)d_out;                  // (4, 512, 512) fp32

  float* Mred  = (float*)((char*)d_ws + MRED_OFF);
  float* vws   = (float*)((char*)d_ws + VWS_OFF);
  float* Mpart = (float*)((char*)d_ws + MPART_OFF);

  if (ws_size >= ws_need(16)) {
    float* vpart = Mpart + mpart_elems(16);
    gemm_m_kernel<16, false><<<NBATCH * 16 * 16, 256, 0, stream>>>(h, e, Mpart, vpart);
    reduce_kernel<16><<<1024, 256, 0, stream>>>(Mpart, vpart, Mred, vws);
  } else if (ws_size >= ws_need(8)) {
    float* vpart = Mpart + mpart_elems(8);
    gemm_m_kernel<8, false><<<NBATCH * 8 * 16, 256, 0, stream>>>(h, e, Mpart, vpart);
    reduce_kernel<8><<<1024, 256, 0, stream>>>(Mpart, vpart, Mred, vws);
  } else {
    hipMemsetAsync(d_ws, 0, VWS_OFF + (size_t)NBATCH * DMODEL * 4, stream);
    gemm_m_kernel<8, true><<<NBATCH * 8 * 16, 256, 0, stream>>>(h, e, Mred, vws);
  }
  gemm_c_kernel<<<NBATCH * 64, 256, 0, stream>>>(Wmat, bias, Mred, vws, out);
}

// Round 6
// 215.317 us; speedup vs baseline: 1.4842x; 1.4842x over previous
//
#include <hip/hip_runtime.h>
#include <hip/hip_bf16.h>
#include <math.h>
#include <stdint.h>

// Problem constants (fixed by the reference)
#define S_LEN  8192
#define DMODEL 512
#define NBATCH 4

// gemm_m tiling
constexpr int BM = 128, BN = 128, BK = 32;
constexpr int PK = 40;                    // padded LDS row stride (shorts); 80 B = 16B-aligned

// gemm_c tiling
constexpr int CBK = 32;
constexpr int PKC = 40;

// Workspace layout (bytes):
//   Mred  @ 0          : 4 MB   (4 x 512 x 512 f32)
//   vws   @ 4MB        : 8 KB   (4 x 512 f32)
//   Mpart @ 4MB+8KB    : NS*16*NBATCH tiles x 64 KB  (NS=16: 64 MB, NS=8: 32 MB)
//   vpart @ after Mpart: NS*NBATCH*4 rows x 2 KB
constexpr size_t MRED_OFF  = 0;
constexpr size_t VWS_OFF   = (size_t)NBATCH * DMODEL * DMODEL * 4;          // 4 MB
constexpr size_t MPART_OFF = VWS_OFF + (size_t)NBATCH * DMODEL * 4;         // +8 KB

__host__ __device__ constexpr size_t mpart_elems(int ns) {
  return (size_t)NBATCH * ns * 16 * (BM * BN);
}
__host__ __device__ constexpr size_t vpart_elems(int ns) {
  return (size_t)ns * NBATCH * 4 * DMODEL;
}
__host__ __device__ constexpr size_t ws_need(int ns) {
  return MPART_OFF + (mpart_elems(ns) + vpart_elems(ns)) * 4;
}

typedef short bfrag  __attribute__((ext_vector_type(8)));   // 8 bf16 (4 VGPRs)
typedef float facc   __attribute__((ext_vector_type(4)));   // 4 fp32 acc

__device__ __forceinline__ unsigned pk2(float a, float b) {
  // packed RNE fp32->bf16 pair; lowers to v_cvt_pk_bf16_f32 on gfx950
  __hip_bfloat162 t = __float22bfloat162_rn(make_float2(a, b));
  union { __hip_bfloat162 h; unsigned u; } cc; cc.h = t; return cc.u;
}

__device__ __forceinline__ void atomAddF(float* p, float v) {
  unsafeAtomicAdd(p, v);
}

__device__ __forceinline__ float selc(const float4& v, int c) {
  return c == 0 ? v.x : c == 1 ? v.y : c == 2 ? v.z : v.w;
}

// ---------------------------------------------------------------------------
// Kernel 1: partial M[b][d'][d] = sum_{t in chunk} w_t h[b][t][d'] e[b][t][d]
// Register-prefetch pipeline; packed bf16 conversion; plain-store epilogue
// (ATOMIC=false) or atomicAdd fallback (ATOMIC=true).
// NOTE: __launch_bounds__ min-waves MUST stay at 2 — the pipeline's register
// working set is ~164 VGPRs; (256,4) caps at 128 and spills the prefetch
// registers to scratch every iteration (R5: WRITE_SIZE 33->340 MB, dur 2x).
// ---------------------------------------------------------------------------
template <int NS, bool ATOMIC>
__global__ __launch_bounds__(256, 2) void gemm_m_kernel(
    const float* __restrict__ h, const float* __restrict__ e,
    float* __restrict__ Mout, float* __restrict__ vout)
{
  __shared__ short Al[BM * PK];
  __shared__ short Bl[BN * PK];

  constexpr int KCH = S_LEN / NS;

  const int blk = blockIdx.x;          // grid = NBATCH * NS * 16
  const int nt  = blk & 3;
  const int mt  = (blk >> 2) & 3;
  const int kt  = (blk >> 4) & (NS - 1);
  const int bb  = blk / (16 * NS);

  const int tid   = threadIdx.x;
  const bool isB  = (tid >= 128);      // wave-uniform (waves 2,3)
  const int hid   = tid & 127;
  const int col4  = (hid & 31) * 4;    // 4-col group within the 128-wide tile
  const int trow  = hid >> 5;          // 0..3 -> t-rows trow*8 .. trow*8+7

  const int wv   = tid >> 6;           // wave 0..3 -> 2x2 of 64x64 subtiles
  const int wm   = wv >> 1, wn = wv & 1;
  const int lane = tid & 63;
  const int lm   = lane & 15, q = lane >> 4;

  const float* src = (isB ? e : h) + (size_t)bb * S_LEN * DMODEL
                   + (isB ? nt * BN : mt * BM) + col4;
  short* ldst = (isB ? Bl : Al) + col4 * PK + trow * 8;

  facc acc[4][4];
#pragma unroll
  for (int i = 0; i < 4; ++i)
#pragma unroll
    for (int j = 0; j < 4; ++j) acc[i][j] = (facc){0.f, 0.f, 0.f, 0.f};

  const float lnA = -(float)M_PI / (float)S_LEN;   // log(alpha), negative
  const int tstart = kt * KCH, tend = tstart + KCH;

  float wbase = __expf(lnA * (float)(S_LEN - 1 - tstart - trow * 8));
  const float stepw = __expf(-lnA * (float)BK);    // alpha^(-32)
  float cr[8];
#pragma unroll
  for (int r = 0; r < 8; ++r)
    cr[r] = __expf(-lnA * (float)r);               // alpha^(-r)

  float4 vacc4 = {0.f, 0.f, 0.f, 0.f};

  // ---- preload iter 0 ----
  float4 cur[8];
  {
    const float* p = src + (size_t)(tstart + trow * 8) * DMODEL;
#pragma unroll
    for (int r = 0; r < 8; ++r) cur[r] = *(const float4*)(p + (size_t)r * DMODEL);
  }

  for (int t0 = tstart; t0 < tend; t0 += BK) {
    // ---- scale (B only) + v accumulate ----
    if (isB) {
#pragma unroll
      for (int r = 0; r < 8; ++r) {
        const float w = wbase * cr[r];
        cur[r].x *= w; cur[r].y *= w; cur[r].z *= w; cur[r].w *= w;
      }
      if (mt == 0) {
#pragma unroll
        for (int r = 0; r < 8; ++r) {
          vacc4.x += cur[r].x; vacc4.y += cur[r].y;
          vacc4.z += cur[r].z; vacc4.w += cur[r].w;
        }
      }
    }
    wbase *= stepw;

    // ---- packed bf16 convert + register transpose (frees cur) ----
    uint4 pk[4];
#pragma unroll
    for (int c = 0; c < 4; ++c) {
      pk[c].x = pk2(selc(cur[0], c), selc(cur[1], c));
      pk[c].y = pk2(selc(cur[2], c), selc(cur[3], c));
      pk[c].z = pk2(selc(cur[4], c), selc(cur[5], c));
      pk[c].w = pk2(selc(cur[6], c), selc(cur[7], c));
    }

    // ---- issue next tile's loads (prefetch distance ~= one iteration) ----
    if (t0 + BK < tend) {
      const float* p = src + (size_t)(t0 + BK + trow * 8) * DMODEL;
#pragma unroll
      for (int r = 0; r < 8; ++r) cur[r] = *(const float4*)(p + (size_t)r * DMODEL);
    }

    __syncthreads();   // previous iteration's frag reads done
#pragma unroll
    for (int c = 0; c < 4; ++c)
      *(uint4*)(ldst + c * PK) = pk[c];
    __syncthreads();

    bfrag af[4], bf[4];
#pragma unroll
    for (int i = 0; i < 4; ++i)
      af[i] = *(const bfrag*)&Al[(wm * 64 + i * 16 + lm) * PK + q * 8];
#pragma unroll
    for (int j = 0; j < 4; ++j)
      bf[j] = *(const bfrag*)&Bl[(wn * 64 + j * 16 + lm) * PK + q * 8];
#pragma unroll
    for (int i = 0; i < 4; ++i)
#pragma unroll
      for (int j = 0; j < 4; ++j)
        acc[i][j] = __builtin_amdgcn_mfma_f32_16x16x32_bf16(af[i], bf[j], acc[i][j], 0, 0, 0);
  }

  if (ATOMIC) {
    float* Mb = Mout + (size_t)bb * DMODEL * DMODEL;
#pragma unroll
    for (int i = 0; i < 4; ++i)
#pragma unroll
      for (int j = 0; j < 4; ++j)
#pragma unroll
        for (int r = 0; r < 4; ++r) {
          const int row = mt * BM + wm * 64 + i * 16 + q * 4 + r;
          const int col = nt * BN + wn * 64 + j * 16 + lm;
          atomAddF(&Mb[(size_t)row * DMODEL + col], acc[i][j][r]);
        }
    if (isB && mt == 0) {
      float* vp = &vout[bb * DMODEL + nt * BN + col4];
      atomAddF(vp + 0, vacc4.x); atomAddF(vp + 1, vacc4.y);
      atomAddF(vp + 2, vacc4.z); atomAddF(vp + 3, vacc4.w);
    }
  } else {
    float* Mp = Mout + (size_t)blk * (BM * BN);
#pragma unroll
    for (int i = 0; i < 4; ++i)
#pragma unroll
      for (int j = 0; j < 4; ++j)
#pragma unroll
        for (int r = 0; r < 4; ++r) {
          const int row = wm * 64 + i * 16 + q * 4 + r;   // local d'
          const int col = wn * 64 + j * 16 + lm;          // local d
          Mp[row * BN + col] = acc[i][j][r];
        }
    if (isB && mt == 0) {
      *(float4*)&vout[(size_t)((kt * NBATCH + bb) * 4 + trow) * DMODEL
                      + nt * BN + col4] = vacc4;
    }
  }
}

// ---------------------------------------------------------------------------
// Reduce: Mred = sum_kt Mpart; vws = sum_{kt,trow} vpart.  262144 threads.
// ---------------------------------------------------------------------------
template <int NS>
__global__ __launch_bounds__(256) void reduce_kernel(
    const float* __restrict__ Mpart, const float* __restrict__ vpart,
    float* __restrict__ Mred, float* __restrict__ vws)
{
  const int gid = blockIdx.x * 256 + threadIdx.x;    // 0 .. 262143 (one float4 each)
  const int bb     = gid >> 16;          // 65536 float4 per batch
  const int rem    = gid & 65535;
  const int tile   = rem >> 12;          // 16 tiles (mt*4+nt)
  const int within = rem & 4095;         // float4 index inside 128x128 tile

  const size_t tilesz = BM * BN;
  const size_t base = ((size_t)(bb * NS) * 16 + tile) * tilesz + (size_t)within * 4;
  float4 s = {0.f, 0.f, 0.f, 0.f};
#pragma unroll
  for (int kt = 0; kt < NS; ++kt) {
    const float4 v = *(const float4*)&Mpart[base + (size_t)kt * 16 * tilesz];
    s.x += v.x; s.y += v.y; s.z += v.z; s.w += v.w;
  }
  const int r = within >> 5;             // local row 0..127
  const int c = (within & 31) * 4;       // local col (float4-aligned)
  const int mt = tile >> 2, nt = tile & 3;
  *(float4*)&Mred[(size_t)bb * DMODEL * DMODEL
                  + (size_t)(mt * BM + r) * DMODEL + nt * BN + c] = s;

  if (gid < (NBATCH * DMODEL / 4)) {     // 512 threads: v reduction
    const int vb = gid >> 7;
    const int vc = (gid & 127) * 4;
    float4 vs = {0.f, 0.f, 0.f, 0.f};
#pragma unroll
    for (int kt = 0; kt < NS; ++kt)
#pragma unroll
      for (int tr = 0; tr < 4; ++tr) {
        const float4 v = *(const float4*)&vpart[(size_t)((kt * NBATCH + vb) * 4 + tr) * DMODEL + vc];
        vs.x += v.x; vs.y += v.y; vs.z += v.z; vs.w += v.w;
      }
    *(float4*)&vws[vb * DMODEL + vc] = vs;
  }
}

// ---------------------------------------------------------------------------
// Kernel 3: C[b][s][d] = sum_{d'} W[s][d'] Mred[b][d'][d] + bias[s]*v[b][d]
// 64x64 tiles, K=512, 16 pipelined iters, plain stores.
// ---------------------------------------------------------------------------
__global__ __launch_bounds__(256) void gemm_c_kernel(
    const float* __restrict__ Wmat, const float* __restrict__ bias,
    const float* __restrict__ Mred, const float* __restrict__ vws,
    float* __restrict__ out)
{
  __shared__ short Wl[64 * PKC];
  __shared__ short Ml[64 * PKC];

  const int blk = blockIdx.x;          // grid = 4 * 8 * 8 = 256
  const int ntc = blk & 7;
  const int mtc = (blk >> 3) & 7;
  const int bb  = blk >> 6;

  const int tid  = threadIdx.x;
  const bool isM = (tid >= 128);
  const int hid  = tid & 127;
  const int arow = hid & 63;           // W-half
  const int ahalf = (hid >> 6) * 16;
  const int mcol4 = (hid & 15) * 4;    // M-half
  const int mrow4 = (hid >> 4) * 4;

  const int wv   = tid >> 6;
  const int lane = tid & 63;
  const int lm   = lane & 15, q = lane >> 4;

  const float* Mb = Mred + (size_t)bb * DMODEL * DMODEL;

  facc acc[4];
#pragma unroll
  for (int j = 0; j < 4; ++j) acc[j] = (facc){0.f, 0.f, 0.f, 0.f};

  float4 cur[4];
  if (!isM) {
    const float* p = &Wmat[(size_t)(mtc * 64 + arow) * DMODEL + ahalf];
#pragma unroll
    for (int r = 0; r < 4; ++r) cur[r] = *(const float4*)(p + r * 4);
  } else {
    const float* p = Mb + (size_t)mrow4 * DMODEL + ntc * 64 + mcol4;
#pragma unroll
    for (int r = 0; r < 4; ++r) cur[r] = *(const float4*)(p + (size_t)r * DMODEL);
  }

  for (int k0 = 0; k0 < DMODEL; k0 += CBK) {
    uint4 pw0, pw1;
    uint2 pm[4];
    if (!isM) {
      pw0.x = pk2(cur[0].x, cur[0].y); pw0.y = pk2(cur[0].z, cur[0].w);
      pw0.z = pk2(cur[1].x, cur[1].y); pw0.w = pk2(cur[1].z, cur[1].w);
      pw1.x = pk2(cur[2].x, cur[2].y); pw1.y = pk2(cur[2].z, cur[2].w);
      pw1.z = pk2(cur[3].x, cur[3].y); pw1.w = pk2(cur[3].z, cur[3].w);
    } else {
#pragma unroll
      for (int c = 0; c < 4; ++c) {
        pm[c].x = pk2(selc(cur[0], c), selc(cur[1], c));
        pm[c].y = pk2(selc(cur[2], c), selc(cur[3], c));
      }
    }

    if (k0 + CBK < DMODEL) {
      if (!isM) {
        const float* p = &Wmat[(size_t)(mtc * 64 + arow) * DMODEL + k0 + CBK + ahalf];
#pragma unroll
        for (int r = 0; r < 4; ++r) cur[r] = *(const float4*)(p + r * 4);
      } else {
        const float* p = Mb + (size_t)(k0 + CBK + mrow4) * DMODEL + ntc * 64 + mcol4;
#pragma unroll
        for (int r = 0; r < 4; ++r) cur[r] = *(const float4*)(p + (size_t)r * DMODEL);
      }
    }

    __syncthreads();
    if (!isM) {
      *(uint4*)&Wl[arow * PKC + ahalf]     = pw0;
      *(uint4*)&Wl[arow * PKC + ahalf + 8] = pw1;
    } else {
#pragma unroll
      for (int c = 0; c < 4; ++c)
        *(uint2*)&Ml[(mcol4 + c) * PKC + mrow4] = pm[c];
    }
    __syncthreads();

    bfrag af, bf[4];
    af = *(const bfrag*)&Wl[(wv * 16 + lm) * PKC + q * 8];
#pragma unroll
    for (int j = 0; j < 4; ++j)
      bf[j] = *(const bfrag*)&Ml[(j * 16 + lm) * PKC + q * 8];
#pragma unroll
    for (int j = 0; j < 4; ++j)
      acc[j] = __builtin_amdgcn_mfma_f32_16x16x32_bf16(af, bf[j], acc[j], 0, 0, 0);
  }

#pragma unroll
  for (int j = 0; j < 4; ++j)
#pragma unroll
    for (int r = 0; r < 4; ++r) {
      const int row = mtc * 64 + wv * 16 + q * 4 + r;   // s
      const int col = ntc * 64 + j * 16 + lm;           // d
      out[((size_t)bb * DMODEL + row) * DMODEL + col] =
          acc[j][r] + bias[row] * vws[bb * DMODEL + col];
    }
}

// ---------------------------------------------------------------------------
extern "C" void kernel_launch(void* const* d_in, const int* in_sizes, int n_in,
                              void* d_out, int out_size, void* d_ws, size_t ws_size,
                              hipStream_t stream) {
  const float* h    = (const float*)d_in[0];   // (4, 8192, 512) fp32
  const float* e    = (const float*)d_in[1];   // (4, 8192, 512) fp32
  const float* Wmat = (const float*)d_in[2];   // (512, 512) fp32
  const float* bias = (const float*)d_in[3];   // (512,) fp32
  float* out = (float*)d_out;                  // (4, 512, 512) fp32

  float* Mred  = (float*)((char*)d_ws + MRED_OFF);
  float* vws   = (float*)((char*)d_ws + VWS_OFF);
  float* Mpart = (float*)((char*)d_ws + MPART_OFF);

  if (ws_size >= ws_need(16)) {
    float* vpart = Mpart + mpart_elems(16);
    gemm_m_kernel<16, false><<<NBATCH * 16 * 16, 256, 0, stream>>>(h, e, Mpart, vpart);
    reduce_kernel<16><<<1024, 256, 0, stream>>>(Mpart, vpart, Mred, vws);
  } else if (ws_size >= ws_need(8)) {
    float* vpart = Mpart + mpart_elems(8);
    gemm_m_kernel<8, false><<<NBATCH * 8 * 16, 256, 0, stream>>>(h, e, Mpart, vpart);
    reduce_kernel<8><<<1024, 256, 0, stream>>>(Mpart, vpart, Mred, vws);
  } else {
    hipMemsetAsync(d_ws, 0, VWS_OFF + (size_t)NBATCH * DMODEL * 4, stream);
    gemm_m_kernel<8, true><<<NBATCH * 8 * 16, 256, 0, stream>>>(h, e, Mred, vws);
  }
  gemm_c_kernel<<<NBATCH * 64, 256, 0, stream>>>(Wmat, bias, Mred, vws, out);
}

// Round 7
// 200.292 us; speedup vs baseline: 1.5955x; 1.0750x over previous
//
#include <hip/hip_runtime.h>
#include <hip/hip_bf16.h>
#include <math.h>
#include <stdint.h>

// Problem constants (fixed by the reference)
#define S_LEN  8192
#define DMODEL 512
#define NBATCH 4

// gemm_m tiling: 256x256 tile, 512 threads (8 waves as 2x4 of 128x64 subtiles)
constexpr int TM = 256, TN = 256, BK = 32;
constexpr int PK = 40;                    // padded LDS row stride (shorts); 80 B, 16B-aligned

// gemm_c tiling
constexpr int CBK = 32;
constexpr int PKC = 40;

// Workspace layout (bytes):
//   Mred  @ 0          : 4 MB   (4 x 512 x 512 f32)
//   vws   @ 4MB        : 8 KB   (4 x 512 f32)
//   Mpart @ 4MB+8KB    : NBATCH*NS*4 tiles x 256 KB  (NS=16: 64 MB)
//   vpart @ after Mpart: NS*NBATCH*4 rows x 2 KB
constexpr size_t MRED_OFF  = 0;
constexpr size_t VWS_OFF   = (size_t)NBATCH * DMODEL * DMODEL * 4;          // 4 MB
constexpr size_t MPART_OFF = VWS_OFF + (size_t)NBATCH * DMODEL * 4;         // +8 KB

__host__ __device__ constexpr size_t mpart_elems(int ns) {
  return (size_t)NBATCH * ns * 4 * (TM * TN);
}
__host__ __device__ constexpr size_t vpart_elems(int ns) {
  return (size_t)ns * NBATCH * 4 * DMODEL;
}
__host__ __device__ constexpr size_t ws_need(int ns) {
  return MPART_OFF + (mpart_elems(ns) + vpart_elems(ns)) * 4;
}

typedef short bfrag  __attribute__((ext_vector_type(8)));   // 8 bf16 (4 VGPRs)
typedef float facc   __attribute__((ext_vector_type(4)));   // 4 fp32 acc

__device__ __forceinline__ unsigned pk2(float a, float b) {
  __hip_bfloat162 t = __float22bfloat162_rn(make_float2(a, b));  // v_cvt_pk_bf16_f32
  union { __hip_bfloat162 h; unsigned u; } cc; cc.h = t; return cc.u;
}

__device__ __forceinline__ void atomAddF(float* p, float v) {
  unsafeAtomicAdd(p, v);
}

__device__ __forceinline__ float selc(const float4& v, int c) {
  return c == 0 ? v.x : c == 1 ? v.y : c == 2 ? v.z : v.w;
}

// ---------------------------------------------------------------------------
// Kernel 1: partial M[b][d'][d] = sum_{t in chunk} w_t h[b][t][d'] e[b][t][d]
// 256x256 tile halves read amplification vs 128x128 (logical reads 512->256MB,
// the R6-measured bandwidth bound). 512 threads: waves 0-3 stage A (h),
// waves 4-7 stage B (e); register-prefetch pipeline; packed bf16 convert.
// Staging index (col4=(hid>>2)*4, trow=hid&3) spreads LDS write banks
// (R6: 8.4M conflict cycles from all-lanes-same-trow 2-bank writes).
// __launch_bounds__(512,2) -> 256 VGPR cap; est. peak ~190 (no spill; R5
// taught us not to cap below the pipeline's working set).
// ---------------------------------------------------------------------------
template <int NS, bool ATOMIC>
__global__ __launch_bounds__(512, 2) void gemm_m_kernel(
    const float* __restrict__ h, const float* __restrict__ e,
    float* __restrict__ Mout, float* __restrict__ vout)
{
  __shared__ short Al[TM * PK];   // 20 KB
  __shared__ short Bl[TN * PK];   // 20 KB

  constexpr int KCH = S_LEN / NS;

  const int blk = blockIdx.x;          // grid = NBATCH * NS * 4
  const int nt  = blk & 1;
  const int mt  = (blk >> 1) & 1;
  const int kt  = (blk >> 2) % NS;
  const int bb  = blk / (4 * NS);

  const int tid   = threadIdx.x;
  const bool isB  = (tid >= 256);      // wave-uniform (waves 4..7)
  const int hid   = tid & 255;
  const int col4  = (hid >> 2) * 4;    // 0..252 within the 256-wide tile
  const int trow  = hid & 3;           // t-rows trow*8 .. trow*8+7

  const int wv   = tid >> 6;           // 8 waves -> 2x4 of 128x64 subtiles
  const int wm   = wv >> 2;            // 0..1 (row half)
  const int wn   = wv & 3;             // 0..3 (col quarter)
  const int lane = tid & 63;
  const int lm   = lane & 15, q = lane >> 4;

  const float* src = (isB ? e : h) + (size_t)bb * S_LEN * DMODEL
                   + (isB ? nt * TN : mt * TM) + col4;
  short* ldst = (isB ? Bl : Al) + col4 * PK + trow * 8;

  facc acc[8][4];
#pragma unroll
  for (int i = 0; i < 8; ++i)
#pragma unroll
    for (int j = 0; j < 4; ++j) acc[i][j] = (facc){0.f, 0.f, 0.f, 0.f};

  const float lnA = -(float)M_PI / (float)S_LEN;   // log(alpha), negative
  const int tstart = kt * KCH, tend = tstart + KCH;

  float wbase = __expf(lnA * (float)(S_LEN - 1 - tstart - trow * 8));
  const float stepw = __expf(-lnA * (float)BK);    // alpha^(-32)
  float cr[8];
#pragma unroll
  for (int r = 0; r < 8; ++r)
    cr[r] = __expf(-lnA * (float)r);               // alpha^(-r)

  float4 vacc4 = {0.f, 0.f, 0.f, 0.f};

  // ---- preload iter 0 ----
  float4 cur[8];
  {
    const float* p = src + (size_t)(tstart + trow * 8) * DMODEL;
#pragma unroll
    for (int r = 0; r < 8; ++r) cur[r] = *(const float4*)(p + (size_t)r * DMODEL);
  }

  for (int t0 = tstart; t0 < tend; t0 += BK) {
    // ---- scale (B only) + v accumulate ----
    if (isB) {
#pragma unroll
      for (int r = 0; r < 8; ++r) {
        const float w = wbase * cr[r];
        cur[r].x *= w; cur[r].y *= w; cur[r].z *= w; cur[r].w *= w;
      }
      if (mt == 0) {
#pragma unroll
        for (int r = 0; r < 8; ++r) {
          vacc4.x += cur[r].x; vacc4.y += cur[r].y;
          vacc4.z += cur[r].z; vacc4.w += cur[r].w;
        }
      }
    }
    wbase *= stepw;

    // ---- packed bf16 convert + register transpose (frees cur) ----
    uint4 pk[4];
#pragma unroll
    for (int c = 0; c < 4; ++c) {
      pk[c].x = pk2(selc(cur[0], c), selc(cur[1], c));
      pk[c].y = pk2(selc(cur[2], c), selc(cur[3], c));
      pk[c].z = pk2(selc(cur[4], c), selc(cur[5], c));
      pk[c].w = pk2(selc(cur[6], c), selc(cur[7], c));
    }

    // ---- issue next tile's loads (prefetch distance ~= one iteration) ----
    if (t0 + BK < tend) {
      const float* p = src + (size_t)(t0 + BK + trow * 8) * DMODEL;
#pragma unroll
      for (int r = 0; r < 8; ++r) cur[r] = *(const float4*)(p + (size_t)r * DMODEL);
    }

    __syncthreads();   // previous iteration's frag reads done
#pragma unroll
    for (int c = 0; c < 4; ++c)
      *(uint4*)(ldst + c * PK) = pk[c];
    __syncthreads();

    bfrag af[8], bf[4];
#pragma unroll
    for (int i = 0; i < 8; ++i)
      af[i] = *(const bfrag*)&Al[(wm * 128 + i * 16 + lm) * PK + q * 8];
#pragma unroll
    for (int j = 0; j < 4; ++j)
      bf[j] = *(const bfrag*)&Bl[(wn * 64 + j * 16 + lm) * PK + q * 8];
#pragma unroll
    for (int i = 0; i < 8; ++i)
#pragma unroll
      for (int j = 0; j < 4; ++j)
        acc[i][j] = __builtin_amdgcn_mfma_f32_16x16x32_bf16(af[i], bf[j], acc[i][j], 0, 0, 0);
  }

  if (ATOMIC) {
    float* Mb = Mout + (size_t)bb * DMODEL * DMODEL;
#pragma unroll
    for (int i = 0; i < 8; ++i)
#pragma unroll
      for (int j = 0; j < 4; ++j)
#pragma unroll
        for (int r = 0; r < 4; ++r) {
          const int row = mt * TM + wm * 128 + i * 16 + q * 4 + r;
          const int col = nt * TN + wn * 64 + j * 16 + lm;
          atomAddF(&Mb[(size_t)row * DMODEL + col], acc[i][j][r]);
        }
    if (isB && mt == 0) {
      float* vp = &vout[bb * DMODEL + nt * TN + col4];
      atomAddF(vp + 0, vacc4.x); atomAddF(vp + 1, vacc4.y);
      atomAddF(vp + 2, vacc4.z); atomAddF(vp + 3, vacc4.w);
    }
  } else {
    float* Mp = Mout + (size_t)blk * (TM * TN);
#pragma unroll
    for (int i = 0; i < 8; ++i)
#pragma unroll
      for (int j = 0; j < 4; ++j)
#pragma unroll
        for (int r = 0; r < 4; ++r) {
          const int row = wm * 128 + i * 16 + q * 4 + r;   // local d'
          const int col = wn * 64 + j * 16 + lm;           // local d
          Mp[row * TN + col] = acc[i][j][r];
        }
    if (isB && mt == 0) {
      *(float4*)&vout[(size_t)((kt * NBATCH + bb) * 4 + trow) * DMODEL
                      + nt * TN + col4] = vacc4;
    }
  }
}

// ---------------------------------------------------------------------------
// Reduce: Mred = sum_kt Mpart; vws = sum_{kt,trow} vpart.  262144 threads.
// Tile order matches gemm_m's blk = bb*(4NS) + kt*4 + (mt*2+nt).
// ---------------------------------------------------------------------------
template <int NS>
__global__ __launch_bounds__(256) void reduce_kernel(
    const float* __restrict__ Mpart, const float* __restrict__ vpart,
    float* __restrict__ Mred, float* __restrict__ vws)
{
  const int gid = blockIdx.x * 256 + threadIdx.x;    // one float4 each
  const int bb     = gid >> 16;          // 65536 float4 per batch
  const int rem    = gid & 65535;
  const int tile   = rem >> 14;          // 4 tiles (mt*2+nt)
  const int within = rem & 16383;        // float4 index inside 256x256 tile

  const size_t tilesz = TM * TN;
  const size_t base = ((size_t)(bb * NS) * 4 + tile) * tilesz + (size_t)within * 4;
  float4 s = {0.f, 0.f, 0.f, 0.f};
#pragma unroll
  for (int kt = 0; kt < NS; ++kt) {
    const float4 v = *(const float4*)&Mpart[base + (size_t)kt * 4 * tilesz];
    s.x += v.x; s.y += v.y; s.z += v.z; s.w += v.w;
  }
  const int r = within >> 6;             // local row 0..255
  const int c = (within & 63) * 4;       // local col (float4-aligned)
  const int mt = tile >> 1, nt = tile & 1;
  *(float4*)&Mred[(size_t)bb * DMODEL * DMODEL
                  + (size_t)(mt * TM + r) * DMODEL + nt * TN + c] = s;

  if (gid < (NBATCH * DMODEL / 4)) {     // 512 threads: v reduction
    const int vb = gid >> 7;
    const int vc = (gid & 127) * 4;
    float4 vs = {0.f, 0.f, 0.f, 0.f};
#pragma unroll
    for (int kt = 0; kt < NS; ++kt)
#pragma unroll
      for (int tr = 0; tr < 4; ++tr) {
        const float4 v = *(const float4*)&vpart[(size_t)((kt * NBATCH + vb) * 4 + tr) * DMODEL + vc];
        vs.x += v.x; vs.y += v.y; vs.z += v.z; vs.w += v.w;
      }
    *(float4*)&vws[vb * DMODEL + vc] = vs;
  }
}

// ---------------------------------------------------------------------------
// Kernel 3: C[b][s][d] = sum_{d'} W[s][d'] Mred[b][d'][d] + bias[s]*v[b][d]
// 64x64 tiles, K=512, 16 pipelined iters, plain stores.
// ---------------------------------------------------------------------------
__global__ __launch_bounds__(256) void gemm_c_kernel(
    const float* __restrict__ Wmat, const float* __restrict__ bias,
    const float* __restrict__ Mred, const float* __restrict__ vws,
    float* __restrict__ out)
{
  __shared__ short Wl[64 * PKC];
  __shared__ short Ml[64 * PKC];

  const int blk = blockIdx.x;          // grid = 4 * 8 * 8 = 256
  const int ntc = blk & 7;
  const int mtc = (blk >> 3) & 7;
  const int bb  = blk >> 6;

  const int tid  = threadIdx.x;
  const bool isM = (tid >= 128);
  const int hid  = tid & 127;
  const int arow = hid & 63;           // W-half
  const int ahalf = (hid >> 6) * 16;
  const int mcol4 = (hid & 15) * 4;    // M-half
  const int mrow4 = (hid >> 4) * 4;

  const int wv   = tid >> 6;
  const int lane = tid & 63;
  const int lm   = lane & 15, q = lane >> 4;

  const float* Mb = Mred + (size_t)bb * DMODEL * DMODEL;

  facc acc[4];
#pragma unroll
  for (int j = 0; j < 4; ++j) acc[j] = (facc){0.f, 0.f, 0.f, 0.f};

  float4 cur[4];
  if (!isM) {
    const float* p = &Wmat[(size_t)(mtc * 64 + arow) * DMODEL + ahalf];
#pragma unroll
    for (int r = 0; r < 4; ++r) cur[r] = *(const float4*)(p + r * 4);
  } else {
    const float* p = Mb + (size_t)mrow4 * DMODEL + ntc * 64 + mcol4;
#pragma unroll
    for (int r = 0; r < 4; ++r) cur[r] = *(const float4*)(p + (size_t)r * DMODEL);
  }

  for (int k0 = 0; k0 < DMODEL; k0 += CBK) {
    uint4 pw0, pw1;
    uint2 pm[4];
    if (!isM) {
      pw0.x = pk2(cur[0].x, cur[0].y); pw0.y = pk2(cur[0].z, cur[0].w);
      pw0.z = pk2(cur[1].x, cur[1].y); pw0.w = pk2(cur[1].z, cur[1].w);
      pw1.x = pk2(cur[2].x, cur[2].y); pw1.y = pk2(cur[2].z, cur[2].w);
      pw1.z = pk2(cur[3].x, cur[3].y); pw1.w = pk2(cur[3].z, cur[3].w);
    } else {
#pragma unroll
      for (int c = 0; c < 4; ++c) {
        pm[c].x = pk2(selc(cur[0], c), selc(cur[1], c));
        pm[c].y = pk2(selc(cur[2], c), selc(cur[3], c));
      }
    }

    if (k0 + CBK < DMODEL) {
      if (!isM) {
        const float* p = &Wmat[(size_t)(mtc * 64 + arow) * DMODEL + k0 + CBK + ahalf];
#pragma unroll
        for (int r = 0; r < 4; ++r) cur[r] = *(const float4*)(p + r * 4);
      } else {
        const float* p = Mb + (size_t)(k0 + CBK + mrow4) * DMODEL + ntc * 64 + mcol4;
#pragma unroll
        for (int r = 0; r < 4; ++r) cur[r] = *(const float4*)(p + (size_t)r * DMODEL);
      }
    }

    __syncthreads();
    if (!isM) {
      *(uint4*)&Wl[arow * PKC + ahalf]     = pw0;
      *(uint4*)&Wl[arow * PKC + ahalf + 8] = pw1;
    } else {
#pragma unroll
      for (int c = 0; c < 4; ++c)
        *(uint2*)&Ml[(mcol4 + c) * PKC + mrow4] = pm[c];
    }
    __syncthreads();

    bfrag af, bf[4];
    af = *(const bfrag*)&Wl[(wv * 16 + lm) * PKC + q * 8];
#pragma unroll
    for (int j = 0; j < 4; ++j)
      bf[j] = *(const bfrag*)&Ml[(j * 16 + lm) * PKC + q * 8];
#pragma unroll
    for (int j = 0; j < 4; ++j)
      acc[j] = __builtin_amdgcn_mfma_f32_16x16x32_bf16(af, bf[j], acc[j], 0, 0, 0);
  }

#pragma unroll
  for (int j = 0; j < 4; ++j)
#pragma unroll
    for (int r = 0; r < 4; ++r) {
      const int row = mtc * 64 + wv * 16 + q * 4 + r;   // s
      const int col = ntc * 64 + j * 16 + lm;           // d
      out[((size_t)bb * DMODEL + row) * DMODEL + col] =
          acc[j][r] + bias[row] * vws[bb * DMODEL + col];
    }
}

// ---------------------------------------------------------------------------
extern "C" void kernel_launch(void* const* d_in, const int* in_sizes, int n_in,
                              void* d_out, int out_size, void* d_ws, size_t ws_size,
                              hipStream_t stream) {
  const float* h    = (const float*)d_in[0];   // (4, 8192, 512) fp32
  const float* e    = (const float*)d_in[1];   // (4, 8192, 512) fp32
  const float* Wmat = (const float*)d_in[2];   // (512, 512) fp32
  const float* bias = (const float*)d_in[3];   // (512,) fp32
  float* out = (float*)d_out;                  // (4, 512, 512) fp32

  float* Mred  = (float*)((char*)d_ws + MRED_OFF);
  float* vws   = (float*)((char*)d_ws + VWS_OFF);
  float* Mpart = (float*)((char*)d_ws + MPART_OFF);

  if (ws_size >= ws_need(16)) {
    float* vpart = Mpart + mpart_elems(16);
    gemm_m_kernel<16, false><<<NBATCH * 16 * 4, 512, 0, stream>>>(h, e, Mpart, vpart);
    reduce_kernel<16><<<1024, 256, 0, stream>>>(Mpart, vpart, Mred, vws);
  } else if (ws_size >= ws_need(8)) {
    float* vpart = Mpart + mpart_elems(8);
    gemm_m_kernel<8, false><<<NBATCH * 8 * 4, 512, 0, stream>>>(h, e, Mpart, vpart);
    reduce_kernel<8><<<1024, 256, 0, stream>>>(Mpart, vpart, Mred, vws);
  } else {
    hipMemsetAsync(d_ws, 0, VWS_OFF + (size_t)NBATCH * DMODEL * 4, stream);
    gemm_m_kernel<16, true><<<NBATCH * 16 * 4, 512, 0, stream>>>(h, e, Mred, vws);
  }
  gemm_c_kernel<<<NBATCH * 64, 256, 0, stream>>>(Wmat, bias, Mred, vws, out);
}